// Round 3
// baseline (355.619 us; speedup 1.0000x reference)
//
#include <hip/hip_runtime.h>
#include <math.h>

// ---- problem constants ----
// D = 640; NET1=[640,512,64]; NET3=[640,640,512,64,512]
// W_TOTAL = 802816 ; B_TOTAL = 1728 ; x2 rows = 804544, each 64 wide
// weight row offsets: L1 wi=0, L2 wi=409600, L3 wi=737280, L4 wi=770048
// bias rows: L1 802816, L2 803456, L3 803968, L4 804032

// workspace layout (float offsets)
#define WS_H0    0      // 640
#define WS_H1N1  640    // 512
#define WS_H1N2  1152   // 512
#define WS_H2    1664   // 64   : "h" for W3
#define WS_INPT  1728   // 640
#define WS_X3A   2368   // 640
#define WS_X3B   3008   // 512
#define WS_X3C   3520   // 64

__device__ __forceinline__ float leaky_f(float v) { return v >= 0.0f ? v : 0.01f * v; }

__device__ __forceinline__ float inpt_at(int i, const float* x, const float* po, const float* st) {
  return i < 64 ? x[i] : (i < 128 ? po[i - 64] : st[i - 128]);
}

// 0.5*tanh(d) = 0.5 - 1/(exp(2d)+1)
__device__ __forceinline__ float half_tanh(float d) {
  float t = exp2f(d * 2.8853900817779268f);  // exp(2d)
  return 0.5f - __builtin_amdgcn_rcpf(t + 1.0f);
}

// float4 dot of a weight row (IN floats) against LDS vector, wave-parallel
template <int IN>
__device__ __forceinline__ float row_dot(const float* __restrict__ wrow, const float* s_in, int lane) {
  const float4* w4 = (const float4*)wrow;
  const float4* s4 = (const float4*)s_in;
  float acc = 0.f;
  for (int j = lane; j < IN / 4; j += 64) {
    float4 a = w4[j];
    float4 b = s4[j];
    acc += a.x * b.x + a.y * b.y + a.z * b.z + a.w * b.w;
  }
  for (int off = 32; off; off >>= 1) acc += __shfl_xor(acc, off, 64);
  return acc;
}

// ---------- K1a: h0 = leaky(net2_w0@inpt+b0) [640], h1n1 = leaky(net1_w0@inpt+b0) [512]
__global__ __launch_bounds__(256) void k1a(const float* __restrict__ x, const float* __restrict__ po,
                                           const float* __restrict__ st,
                                           const float* __restrict__ w2_0, const float* __restrict__ b2_0,
                                           const float* __restrict__ w1_0, const float* __restrict__ b1_0,
                                           float* __restrict__ ws) {
  __shared__ __align__(16) float s_in[640];
  for (int i = threadIdx.x; i < 640; i += 256) {
    float v = inpt_at(i, x, po, st);
    s_in[i] = v;
    ws[WS_INPT + i] = v;
  }
  __syncthreads();
  int wave = threadIdx.x >> 6, lane = threadIdx.x & 63;
  int o = blockIdx.x * 4 + wave;  // 0..1151
  const float* wrow;
  float bias;
  float* dst;
  if (o < 640) {
    wrow = w2_0 + (long long)o * 640; bias = b2_0[o]; dst = ws + WS_H0 + o;
  } else {
    int oo = o - 640;
    wrow = w1_0 + (long long)oo * 640; bias = b1_0[oo]; dst = ws + WS_H1N1 + oo;
  }
  float acc = row_dot<640>(wrow, s_in, lane);
  if (lane == 0) *dst = leaky_f(acc + bias);
}

// ---------- K1b: h1n2 = leaky(net2_w1@h0+b1) [512] ; out = net1_w1@h1n1+b1 [64]
__global__ __launch_bounds__(256) void k1b(const float* __restrict__ w2_1, const float* __restrict__ b2_1,
                                           const float* __restrict__ w1_1, const float* __restrict__ b1_1,
                                           float* __restrict__ ws, float* __restrict__ out) {
  __shared__ __align__(16) float s_h0[640];
  __shared__ __align__(16) float s_h1[512];
  for (int i = threadIdx.x; i < 640; i += 256) s_h0[i] = ws[WS_H0 + i];
  for (int i = threadIdx.x; i < 512; i += 256) s_h1[i] = ws[WS_H1N1 + i];
  __syncthreads();
  int wave = threadIdx.x >> 6, lane = threadIdx.x & 63;
  int o = blockIdx.x * 4 + wave;  // 0..575
  if (o < 512) {
    float acc = row_dot<640>(w2_1 + (long long)o * 640, s_h0, lane);
    if (lane == 0) ws[WS_H1N2 + o] = leaky_f(acc + b2_1[o]);
  } else {
    int oo = o - 512;
    float acc = row_dot<512>(w1_1 + (long long)oo * 512, s_h1, lane);
    if (lane == 0) out[oo] = acc + b1_1[oo];
  }
}

// ---------- K1c: h2 = leaky(net2_w2@h1n2+b2) [64]
__global__ __launch_bounds__(256) void k1c(const float* __restrict__ w2_2, const float* __restrict__ b2_2,
                                           float* __restrict__ ws) {
  __shared__ __align__(16) float s_h[512];
  for (int i = threadIdx.x; i < 512; i += 256) s_h[i] = ws[WS_H1N2 + i];
  __syncthreads();
  int wave = threadIdx.x >> 6, lane = threadIdx.x & 63;
  int o = blockIdx.x * 4 + wave;  // 0..63
  float acc = row_dot<512>(w2_2 + (long long)o * 512, s_h, lane);
  if (lane == 0) ws[WS_H2 + o] = leaky_f(acc + b2_2[o]);
}

// ---------- K2c: fused generated layer, COALESCED.
// One block (512 threads = 8 waves) per output neuron o.
// A wave processes 4 consecutive rows per step: 16 lanes cooperate on one row,
// lane l loads float4 #(l&15) of row (step*32 + wave*4 + (l>>4)).
// Wave-level load = 1 KB contiguous. Each lane holds h[(l&15)*4 .. +3] only.
template <int IN_D, bool LEAKY>
__global__ __launch_bounds__(512) void k2c(const float* __restrict__ w3, const float* __restrict__ b3,
                                           const float* __restrict__ h2p, const float* __restrict__ x3in,
                                           float* __restrict__ x3out, long long wi, long long brow) {
  __shared__ __align__(16) float s_in[IN_D];
  __shared__ float s_red[8];
  const int tid = threadIdx.x;
  const int wave = tid >> 6, lane = tid & 63;
  const int g = lane >> 4;    // row-group within wave (0..3)
  const int gl = lane & 15;   // lane within group

  float4 hv = ((const float4*)h2p)[gl];  // this lane's 16B slice of h
  for (int i = tid; i < IN_D; i += 512) s_in[i] = x3in[i];
  __syncthreads();

  const int o = blockIdx.x;
  const long long rowbase = wi + (long long)o * IN_D;
  float acc = 0.0f;
  constexpr int STEPS = IN_D / 32;  // 32 rows per block-step (8 waves x 4 rows)
#pragma unroll
  for (int s = 0; s < STEPS; s++) {
    int rl = s * 32 + wave * 4 + g;  // local row index (input index i)
    long long r = rowbase + rl;
    float4 v = ((const float4*)(w3 + (r << 6)))[gl];
    float d = v.x * hv.x + v.y * hv.y + v.z * hv.z + v.w * hv.w;
    d += __shfl_xor(d, 1, 64);
    d += __shfl_xor(d, 2, 64);
    d += __shfl_xor(d, 4, 64);
    d += __shfl_xor(d, 8, 64);
    d += b3[r];
    float x2v = half_tanh(d);
    if (gl == 0) acc += x2v * s_in[rl];
  }
  // generated bias row (brow + o): wave 0, lanes 0..15
  if (wave == 0 && lane < 16) {
    long long rb = brow + o;
    float4 v = ((const float4*)(w3 + (rb << 6)))[gl];
    float d = v.x * hv.x + v.y * hv.y + v.z * hv.z + v.w * hv.w;
    d += __shfl_xor(d, 1, 64);
    d += __shfl_xor(d, 2, 64);
    d += __shfl_xor(d, 4, 64);
    d += __shfl_xor(d, 8, 64);
    d += b3[rb];
    if (lane == 0) acc += half_tanh(d);
  }
  // block reduction
  for (int off = 32; off; off >>= 1) acc += __shfl_xor(acc, off, 64);
  if (lane == 0) s_red[wave] = acc;
  __syncthreads();
  if (tid == 0) {
    float tot = 0.f;
#pragma unroll
    for (int w = 0; w < 8; w++) tot += s_red[w];
    x3out[o] = LEAKY ? leaky_f(tot) : tot;
  }
}

extern "C" void kernel_launch(void* const* d_in, const int* in_sizes, int n_in,
                              void* d_out, int out_size, void* d_ws, size_t ws_size,
                              hipStream_t stream) {
  const float* x    = (const float*)d_in[0];
  const float* po   = (const float*)d_in[1];
  const float* st   = (const float*)d_in[2];
  const float* w1_0 = (const float*)d_in[3];
  const float* b1_0 = (const float*)d_in[4];
  const float* w1_1 = (const float*)d_in[5];
  const float* b1_1 = (const float*)d_in[6];
  const float* w2_0 = (const float*)d_in[7];
  const float* b2_0 = (const float*)d_in[8];
  const float* w2_1 = (const float*)d_in[9];
  const float* b2_1 = (const float*)d_in[10];
  const float* w2_2 = (const float*)d_in[11];
  const float* b2_2 = (const float*)d_in[12];
  const float* w3   = (const float*)d_in[13];
  const float* b3   = (const float*)d_in[14];
  float* ws  = (float*)d_ws;
  float* out = (float*)d_out;

  k1a<<<288, 256, 0, stream>>>(x, po, st, w2_0, b2_0, w1_0, b1_0, ws);
  k1b<<<144, 256, 0, stream>>>(w2_1, b2_1, w1_1, b1_1, ws, out);
  k1c<<<16, 256, 0, stream>>>(w2_2, b2_2, ws);
  // generated layer 1: out 640, in 640
  k2c<640, true><<<640, 512, 0, stream>>>(w3, b3, ws + WS_H2, ws + WS_INPT, ws + WS_X3A, 0LL, 802816LL);
  // generated layer 2: out 512, in 640
  k2c<640, true><<<512, 512, 0, stream>>>(w3, b3, ws + WS_H2, ws + WS_X3A, ws + WS_X3B, 409600LL, 803456LL);
  // generated layer 3: out 64, in 512
  k2c<512, true><<<64, 512, 0, stream>>>(w3, b3, ws + WS_H2, ws + WS_X3B, ws + WS_X3C, 737280LL, 803968LL);
  // generated layer 4: out 512, in 64 -> d_out[64:576], no activation
  k2c<64, false><<<512, 512, 0, stream>>>(w3, b3, ws + WS_H2, ws + WS_X3C, out + 64, 770048LL, 804032LL);
}

// Round 4
// 339.996 us; speedup vs baseline: 1.0460x; 1.0460x over previous
//
#include <hip/hip_runtime.h>
#include <math.h>

// ---- problem constants ----
// D = 640; NET1=[640,512,64]; NET3=[640,640,512,64,512]
// W_TOTAL = 802816 ; B_TOTAL = 1728 ; x2 rows = 804544, each 64 wide
// weight row offsets: L1 wi=0, L2 wi=409600, L3 wi=737280, L4 wi=770048
// bias rows: L1 802816, L2 803456, L3 803968, L4 804032

// workspace layout (float offsets)
#define WS_H0    0      // 640
#define WS_H1N1  640    // 512
#define WS_H1N2  1152   // 512
#define WS_H2    1664   // 64   : "h" for W3
#define WS_INPT  1728   // 640
#define WS_X3A   2368   // 640
#define WS_X3B   3008   // 512
#define WS_X3C   3520   // 64
#define WS_T     4096   // 804544 : t[r] = 0.5*tanh(w3[r]·h + b3[r])

#define N_ROWS   804544
#define N_WAVES  12571   // N_ROWS / 64

__device__ __forceinline__ float leaky_f(float v) { return v >= 0.0f ? v : 0.01f * v; }

__device__ __forceinline__ float inpt_at(int i, const float* x, const float* po, const float* st) {
  return i < 64 ? x[i] : (i < 128 ? po[i - 64] : st[i - 128]);
}

// 0.5*tanh(d) = 0.5 - 1/(exp(2d)+1)
__device__ __forceinline__ float half_tanh(float d) {
  float t = exp2f(d * 2.8853900817779268f);  // exp(2d)
  return 0.5f - __builtin_amdgcn_rcpf(t + 1.0f);
}

// float4 dot of a row (IN floats) against LDS vector, wave-parallel
template <int IN>
__device__ __forceinline__ float row_dot(const float* __restrict__ wrow, const float* s_in, int lane) {
  const float4* w4 = (const float4*)wrow;
  const float4* s4 = (const float4*)s_in;
  float acc = 0.f;
  for (int j = lane; j < IN / 4; j += 64) {
    float4 a = w4[j];
    float4 b = s4[j];
    acc += a.x * b.x + a.y * b.y + a.z * b.z + a.w * b.w;
  }
  for (int off = 32; off; off >>= 1) acc += __shfl_xor(acc, off, 64);
  return acc;
}

// ---------- K1a: h0 = leaky(net2_w0@inpt+b0) [640], h1n1 = leaky(net1_w0@inpt+b0) [512]
__global__ __launch_bounds__(256) void k1a(const float* __restrict__ x, const float* __restrict__ po,
                                           const float* __restrict__ st,
                                           const float* __restrict__ w2_0, const float* __restrict__ b2_0,
                                           const float* __restrict__ w1_0, const float* __restrict__ b1_0,
                                           float* __restrict__ ws) {
  __shared__ __align__(16) float s_in[640];
  for (int i = threadIdx.x; i < 640; i += 256) {
    float v = inpt_at(i, x, po, st);
    s_in[i] = v;
    ws[WS_INPT + i] = v;
  }
  __syncthreads();
  int wave = threadIdx.x >> 6, lane = threadIdx.x & 63;
  int o = blockIdx.x * 4 + wave;  // 0..1151
  const float* wrow;
  float bias;
  float* dst;
  if (o < 640) {
    wrow = w2_0 + (long long)o * 640; bias = b2_0[o]; dst = ws + WS_H0 + o;
  } else {
    int oo = o - 640;
    wrow = w1_0 + (long long)oo * 640; bias = b1_0[oo]; dst = ws + WS_H1N1 + oo;
  }
  float acc = row_dot<640>(wrow, s_in, lane);
  if (lane == 0) *dst = leaky_f(acc + bias);
}

// ---------- K1b: h1n2 = leaky(net2_w1@h0+b1) [512] ; out = net1_w1@h1n1+b1 [64]
__global__ __launch_bounds__(256) void k1b(const float* __restrict__ w2_1, const float* __restrict__ b2_1,
                                           const float* __restrict__ w1_1, const float* __restrict__ b1_1,
                                           float* __restrict__ ws, float* __restrict__ out) {
  __shared__ __align__(16) float s_h0[640];
  __shared__ __align__(16) float s_h1[512];
  for (int i = threadIdx.x; i < 640; i += 256) s_h0[i] = ws[WS_H0 + i];
  for (int i = threadIdx.x; i < 512; i += 256) s_h1[i] = ws[WS_H1N1 + i];
  __syncthreads();
  int wave = threadIdx.x >> 6, lane = threadIdx.x & 63;
  int o = blockIdx.x * 4 + wave;  // 0..575
  if (o < 512) {
    float acc = row_dot<640>(w2_1 + (long long)o * 640, s_h0, lane);
    if (lane == 0) ws[WS_H1N2 + o] = leaky_f(acc + b2_1[o]);
  } else {
    int oo = o - 512;
    float acc = row_dot<512>(w1_1 + (long long)oo * 512, s_h1, lane);
    if (lane == 0) out[oo] = acc + b1_1[oo];
  }
}

// ---------- K1c: h2 = leaky(net2_w2@h1n2+b2) [64]
__global__ __launch_bounds__(256) void k1c(const float* __restrict__ w2_2, const float* __restrict__ b2_2,
                                           float* __restrict__ ws) {
  __shared__ __align__(16) float s_h[512];
  for (int i = threadIdx.x; i < 512; i += 256) s_h[i] = ws[WS_H1N2 + i];
  __syncthreads();
  int wave = threadIdx.x >> 6, lane = threadIdx.x & 63;
  int o = blockIdx.x * 4 + wave;  // 0..63
  float acc = row_dot<512>(w2_2 + (long long)o * 512, s_h, lane);
  if (lane == 0) ws[WS_H2 + o] = leaky_f(acc + b2_2[o]);
}

// ---------- bigT: t[r] = 0.5*tanh(w3[r,:]·h + b3[r]) for ALL 804544 rows.
// Zero inter-row dependency; one wave per 64 consecutive rows.
// 16 lanes cooperate per row (lane gl holds h[gl*4..+3]); per wave, 16
// independent coalesced dwordx4 loads (4 KB) in flight, then 16 dot+butterfly.
__global__ __launch_bounds__(256) void bigT(const float* __restrict__ w3, const float* __restrict__ b3,
                                            const float* __restrict__ h2p, float* __restrict__ t) {
  int wid = blockIdx.x * 4 + (threadIdx.x >> 6);
  if (wid >= N_WAVES) return;  // no barriers below: early return safe
  const int lane = threadIdx.x & 63;
  const int g = lane >> 4;    // row-in-quad (0..3)
  const int gl = lane & 15;   // float4-slot within row
  float4 hv = ((const float4*)h2p)[gl];
  const long long base = (long long)wid * 64;
  const float4* wp = (const float4*)(w3 + (base << 6));  // 64 rows x 16 float4
  float4 v[16];
#pragma unroll
  for (int q = 0; q < 16; q++) v[q] = wp[((q * 4 + g) << 4) + gl];
#pragma unroll
  for (int q = 0; q < 16; q++) {
    float d = v[q].x * hv.x + v[q].y * hv.y + v[q].z * hv.z + v[q].w * hv.w;
    d += __shfl_xor(d, 1, 64);
    d += __shfl_xor(d, 2, 64);
    d += __shfl_xor(d, 4, 64);
    d += __shfl_xor(d, 8, 64);
    if (gl == 0) {
      long long r = base + q * 4 + g;
      t[r] = half_tanh(d + b3[r]);
    }
  }
}

// ---------- gml: generated layer from precomputed t (L2-resident, 3.2 MB).
// x3out[o] = act( dot(t[wi+o*IN .. ], x3in) + t[brow+o] ), wave per output.
template <int IN, bool LEAKY>
__global__ __launch_bounds__(256) void gml(const float* __restrict__ t, const float* __restrict__ x3in,
                                           float* __restrict__ x3out, long long wi, long long brow,
                                           int OUT) {
  __shared__ __align__(16) float s_in[IN];
  for (int i = threadIdx.x; i < IN; i += 256) s_in[i] = x3in[i];
  __syncthreads();
  int wave = threadIdx.x >> 6, lane = threadIdx.x & 63;
  int o = blockIdx.x * 4 + wave;
  if (o >= OUT) return;
  float acc = row_dot<IN>(t + wi + (long long)o * IN, s_in, lane);
  if (lane == 0) {
    acc += t[brow + o];  // generated bias
    x3out[o] = LEAKY ? leaky_f(acc) : acc;
  }
}

extern "C" void kernel_launch(void* const* d_in, const int* in_sizes, int n_in,
                              void* d_out, int out_size, void* d_ws, size_t ws_size,
                              hipStream_t stream) {
  const float* x    = (const float*)d_in[0];
  const float* po   = (const float*)d_in[1];
  const float* st   = (const float*)d_in[2];
  const float* w1_0 = (const float*)d_in[3];
  const float* b1_0 = (const float*)d_in[4];
  const float* w1_1 = (const float*)d_in[5];
  const float* b1_1 = (const float*)d_in[6];
  const float* w2_0 = (const float*)d_in[7];
  const float* b2_0 = (const float*)d_in[8];
  const float* w2_1 = (const float*)d_in[9];
  const float* b2_1 = (const float*)d_in[10];
  const float* w2_2 = (const float*)d_in[11];
  const float* b2_2 = (const float*)d_in[12];
  const float* w3   = (const float*)d_in[13];
  const float* b3   = (const float*)d_in[14];
  float* ws  = (float*)d_ws;
  float* out = (float*)d_out;
  float* t   = ws + WS_T;

  k1a<<<288, 256, 0, stream>>>(x, po, st, w2_0, b2_0, w1_0, b1_0, ws);
  k1b<<<144, 256, 0, stream>>>(w2_1, b2_1, w1_1, b1_1, ws, out);
  k1c<<<16, 256, 0, stream>>>(w2_2, b2_2, ws);
  // the one heavy kernel: 206 MB streamed, fully parallel
  bigT<<<(N_WAVES + 3) / 4, 256, 0, stream>>>(w3, b3, ws + WS_H2, t);
  // generated net on L2-resident t
  gml<640, true><<<160, 256, 0, stream>>>(t, ws + WS_INPT, ws + WS_X3A, 0LL, 802816LL, 640);
  gml<640, true><<<128, 256, 0, stream>>>(t, ws + WS_X3A, ws + WS_X3B, 409600LL, 803456LL, 512);
  gml<512, true><<<16, 256, 0, stream>>>(t, ws + WS_X3B, ws + WS_X3C, 737280LL, 803968LL, 64);
  gml<64, false><<<128, 256, 0, stream>>>(t, ws + WS_X3C, out + 64, 770048LL, 804032LL, 512);
}